// Round 1
// baseline (357.072 us; speedup 1.0000x reference)
//
#include <hip/hip_runtime.h>

#define B_ 8
#define T_ 8192
#define D_ 1024
#define GD_ 64
#define WSZ_ 16
#define NWIN_ (T_ / WSZ_)   // 512

// ---------------------------------------------------------------------------
// K1: g = normalize(relu(z @ W1) @ W2)  -- f64 accumulation, f32 rounding at
// the same points the numpy reference rounds (H and G), to track the
// reference's decision-critical sim values as closely as possible.
// grid: (B*T)/64 blocks, 256 threads. Each block: 64 tokens x 64 outputs.
// ---------------------------------------------------------------------------
__global__ __launch_bounds__(256) void k_compute_g(
    const float* __restrict__ z, const float* __restrict__ W1,
    const float* __restrict__ W2, float* __restrict__ g_out)
{
  __shared__ float Zs[64][65];   // phase A: z tile [token][k]; phase B: H tile
  __shared__ float Ws[64][64];   // phase A: W1 tile [k][n];   phase B: W2

  const int tid = threadIdx.x;
  const int r = tid >> 4;        // 0..15 -> tokens 4r..4r+3
  const int c = tid & 15;        // 0..15 -> outputs 4c..4c+3
  const long bt0 = (long)blockIdx.x * 64;

  double acc[4][4];
#pragma unroll
  for (int i = 0; i < 4; ++i)
#pragma unroll
    for (int j = 0; j < 4; ++j) acc[i][j] = 0.0;

  for (int k0 = 0; k0 < D_; k0 += 64) {
#pragma unroll
    for (int it = 0; it < 4; ++it) {
      const int idx = tid + 256 * it;
      const int row = idx >> 4, c4 = idx & 15;
      const float4 zv = *(const float4*)(z + (bt0 + row) * D_ + k0 + c4 * 4);
      Zs[row][c4 * 4 + 0] = zv.x; Zs[row][c4 * 4 + 1] = zv.y;
      Zs[row][c4 * 4 + 2] = zv.z; Zs[row][c4 * 4 + 3] = zv.w;
      *(float4*)&Ws[row][c4 * 4] =
          *(const float4*)(W1 + (k0 + row) * GD_ + c4 * 4);
    }
    __syncthreads();
#pragma unroll 4
    for (int k = 0; k < 64; ++k) {
      float zz[4], ww[4];
      zz[0] = Zs[4 * r + 0][k]; zz[1] = Zs[4 * r + 1][k];
      zz[2] = Zs[4 * r + 2][k]; zz[3] = Zs[4 * r + 3][k];
      const float4 wv = *(const float4*)&Ws[k][4 * c];
      ww[0] = wv.x; ww[1] = wv.y; ww[2] = wv.z; ww[3] = wv.w;
#pragma unroll
      for (int i = 0; i < 4; ++i)
#pragma unroll
        for (int j = 0; j < 4; ++j)
          acc[i][j] += (double)zz[i] * (double)ww[j];
    }
    __syncthreads();
  }

  // H = relu(z@W1), rounded to f32 (as the reference's f32 pipeline does)
#pragma unroll
  for (int i = 0; i < 4; ++i)
#pragma unroll
    for (int j = 0; j < 4; ++j) {
      const double h = acc[i][j] > 0.0 ? acc[i][j] : 0.0;
      Zs[4 * r + i][4 * c + j] = (float)h;
    }
#pragma unroll
  for (int it = 0; it < 4; ++it) {
    const int idx = tid + 256 * it;
    const int row = idx >> 4, c4 = idx & 15;
    *(float4*)&Ws[row][c4 * 4] = *(const float4*)(W2 + row * GD_ + c4 * 4);
  }
  __syncthreads();

  double acc2[4][4];
#pragma unroll
  for (int i = 0; i < 4; ++i)
#pragma unroll
    for (int j = 0; j < 4; ++j) acc2[i][j] = 0.0;

#pragma unroll 4
  for (int k = 0; k < 64; ++k) {
    float hh[4], ww[4];
    hh[0] = Zs[4 * r + 0][k]; hh[1] = Zs[4 * r + 1][k];
    hh[2] = Zs[4 * r + 2][k]; hh[3] = Zs[4 * r + 3][k];
    const float4 wv = *(const float4*)&Ws[k][4 * c];
    ww[0] = wv.x; ww[1] = wv.y; ww[2] = wv.z; ww[3] = wv.w;
#pragma unroll
    for (int i = 0; i < 4; ++i)
#pragma unroll
      for (int j = 0; j < 4; ++j)
        acc2[i][j] += (double)hh[i] * (double)ww[j];
  }

  // Round G to f32, then f64 norm of the rounded values, divide, store f32.
#pragma unroll
  for (int i = 0; i < 4; ++i) {
    float gf[4];
#pragma unroll
    for (int j = 0; j < 4; ++j) gf[j] = (float)acc2[i][j];
    double ss = 0.0;
#pragma unroll
    for (int j = 0; j < 4; ++j) ss += (double)gf[j] * (double)gf[j];
#pragma unroll
    for (int m = 1; m < 16; m <<= 1) ss += __shfl_xor(ss, m);
    const double denom = sqrt(ss) + 1e-8;
    float4 o;
    o.x = (float)((double)gf[0] / denom);
    o.y = (float)((double)gf[1] / denom);
    o.z = (float)((double)gf[2] / denom);
    o.w = (float)((double)gf[3] / denom);
    *(float4*)(g_out + (bt0 + 4 * r + i) * GD_ + 4 * c) = o;
  }
}

// ---------------------------------------------------------------------------
// K2: per-window sims (f64 lane-parallel dots) + stable sort + budgeted greedy
// grid: B*NWIN blocks, 64 threads (1 wave)
// ---------------------------------------------------------------------------
__global__ __launch_bounds__(64) void k_sim_pick(
    const float* __restrict__ g, const int* __restrict__ tlptr,
    int* __restrict__ mrMask, int* __restrict__ keptCnt)
{
  const int bw = blockIdx.x;
  const int b = bw / NWIN_, w = bw % NWIN_;
  const int lane = threadIdx.x;
  const float* gr = g + ((long)b * T_ + (long)w * WSZ_) * GD_;

  __shared__ double sims[WSZ_ - 1];

  double a = (double)gr[lane];
#pragma unroll
  for (int e = 0; e < WSZ_ - 1; ++e) {
    const double bv = (double)gr[(e + 1) * GD_ + lane];
    double p = a * bv;
#pragma unroll
    for (int m = 32; m >= 1; m >>= 1) p += __shfl_xor(p, m);
    if (lane == 0) sims[e] = p;
    a = bv;
  }
  __syncthreads();

  if (lane == 0) {
    const int tl = tlptr[0];
    const int mn = T_ - tl;
    const int base = mn / NWIN_, extra = mn % NWIN_;
    int budget = base + (w < extra ? 1 : 0);
    if (budget > WSZ_ / 2) budget = WSZ_ / 2;
    if (budget < 0) budget = 0;

    double v[WSZ_ - 1];
    int id[WSZ_ - 1];
    for (int e = 0; e < WSZ_ - 1; ++e) { v[e] = sims[e]; id[e] = e; }
    // stable insertion sort, descending by value (ties keep smaller index)
    for (int i = 1; i < WSZ_ - 1; ++i) {
      const double dv = v[i]; const int di = id[i];
      int j = i - 1;
      while (j >= 0 && v[j] < dv) { v[j + 1] = v[j]; id[j + 1] = id[j]; --j; }
      v[j + 1] = dv; id[j + 1] = di;
    }
    bool used[WSZ_];
    for (int i = 0; i < WSZ_; ++i) used[i] = false;
    int mrm = 0, picked = 0;
    for (int ii = 0; ii < WSZ_ - 1; ++ii) {
      const int e = id[ii];
      if (picked < budget && !used[e] && !used[e + 1]) {
        used[e] = used[e + 1] = true;
        mrm |= (1 << (e + 1));
        ++picked;
      }
    }
    mrMask[bw] = mrm;
    keptCnt[bw] = WSZ_ - picked;
  }
}

// ---------------------------------------------------------------------------
// K3: per-batch exclusive prefix over window kept-counts (tiny)
// ---------------------------------------------------------------------------
__global__ void k_scan_windows(const int* __restrict__ keptCnt,
                               int* __restrict__ outOff)
{
  const int b = threadIdx.x;
  if (b >= B_) return;
  int off = 0;
  for (int w = 0; w < NWIN_; ++w) {
    outOff[b * NWIN_ + w] = off;
    off += keptCnt[b * NWIN_ + w];
  }
}

// ---------------------------------------------------------------------------
// K4: emit z_new rows + lens_new.  grid: B*NWIN blocks, 256 threads.
// ---------------------------------------------------------------------------
__global__ __launch_bounds__(256) void k_emit(
    const float* __restrict__ z, const int* __restrict__ lens,
    const int* __restrict__ mrMask, const int* __restrict__ outOff,
    float* __restrict__ out, int TL)
{
  const int bw = blockIdx.x;
  const int b = bw / NWIN_, w = bw % NWIN_;
  const int tid = threadIdx.x;
  const int mrm = mrMask[bw];
  int p = outOff[bw];
  const int t0 = w * WSZ_;

  const float* zb = z + (long)b * T_ * D_;
  const int* lb = lens + b * T_;
  float* zout = out;
  float* lout = out + (long)B_ * TL * D_;

  for (int i = 0; i < WSZ_; ++i) {
    if ((mrm >> i) & 1) continue;   // dropped token
    if (p >= TL) return;            // uniform across block
    const int t = t0 + i;
    const bool ab = (i < WSZ_ - 1) && ((mrm >> (i + 1)) & 1);
    float4 o = *(const float4*)(zb + (long)t * D_ + tid * 4);
    if (ab) {
      const float wi = (float)lb[t], wj = (float)lb[t + 1];
      const float s = wi + wj;
      const float4 zj = *(const float4*)(zb + (long)(t + 1) * D_ + tid * 4);
      o.x = (o.x * wi + zj.x * wj) / s;
      o.y = (o.y * wi + zj.y * wj) / s;
      o.z = (o.z * wi + zj.z * wj) / s;
      o.w = (o.w * wi + zj.w * wj) / s;
      if (tid == 0) lout[(long)b * TL + p] = s;
    } else {
      if (tid == 0) lout[(long)b * TL + p] = (float)lb[t];
    }
    *(float4*)(zout + ((long)b * TL + p) * D_ + tid * 4) = o;
    ++p;
  }
}

// ---------------------------------------------------------------------------
// K5: starts = exclusive cumsum of lens_new per row. grid: B blocks, 256 thr.
// ---------------------------------------------------------------------------
__global__ __launch_bounds__(256) void k_starts(
    const float* __restrict__ lens_f, float* __restrict__ starts, int TL)
{
  const int b = blockIdx.x;
  const int tid = threadIdx.x;
  const int lane = tid & 63, wv = tid >> 6;
  __shared__ float wsum[4];
  const float* lrow = lens_f + (long)b * TL;
  float* srow = starts + (long)b * TL;
  float carry = 0.0f;

  for (int c0 = 0; c0 < TL; c0 += 256) {
    const int j = c0 + tid;
    const float v = (j < TL) ? lrow[j] : 0.0f;
    float x = v;
#pragma unroll
    for (int d = 1; d < 64; d <<= 1) {
      const float o = __shfl_up(x, d);
      if (lane >= d) x += o;
    }
    if (lane == 63) wsum[wv] = x;
    __syncthreads();
    float pre = 0.0f;
    if (wv > 0) pre += wsum[0];
    if (wv > 1) pre += wsum[1];
    if (wv > 2) pre += wsum[2];
    const float tot = wsum[0] + wsum[1] + wsum[2] + wsum[3];
    if (j < TL) srow[j] = carry + pre + x - v;
    carry += tot;
    __syncthreads();
  }
}

// ---------------------------------------------------------------------------
extern "C" void kernel_launch(void* const* d_in, const int* in_sizes, int n_in,
                              void* d_out, int out_size, void* d_ws, size_t ws_size,
                              hipStream_t stream)
{
  const float* z    = (const float*)d_in[0];
  const int*   lens = (const int*)d_in[1];
  const float* W1   = (const float*)d_in[2];
  const float* W2   = (const float*)d_in[3];
  const int*   tlp  = (const int*)d_in[4];

  float* out = (float*)d_out;
  // out_size = B*TL*D + B*TL + B*TL  ->  TL
  const int TL = out_size / (B_ * (D_ + 2));

  // workspace layout
  float* g      = (float*)d_ws;                               // B*T*GD f32 = 16 MB
  int*   mrMask = (int*)((char*)d_ws + (size_t)B_ * T_ * GD_ * 4);
  int*   kept   = mrMask + B_ * NWIN_;
  int*   outOff = kept + B_ * NWIN_;

  hipLaunchKernelGGL(k_compute_g, dim3((B_ * T_) / 64), dim3(256), 0, stream,
                     z, W1, W2, g);
  hipLaunchKernelGGL(k_sim_pick, dim3(B_ * NWIN_), dim3(64), 0, stream,
                     g, tlp, mrMask, kept);
  hipLaunchKernelGGL(k_scan_windows, dim3(1), dim3(64), 0, stream,
                     kept, outOff);
  hipLaunchKernelGGL(k_emit, dim3(B_ * NWIN_), dim3(256), 0, stream,
                     z, lens, mrMask, outOff, out, TL);
  hipLaunchKernelGGL(k_starts, dim3(B_), dim3(256), 0, stream,
                     out + (long)B_ * TL * D_,
                     out + (long)B_ * TL * D_ + (long)B_ * TL, TL);
}

// Round 2
// 304.708 us; speedup vs baseline: 1.1718x; 1.1718x over previous
//
#include <hip/hip_runtime.h>

#define B_ 8
#define T_ 8192
#define D_ 1024
#define GD_ 64
#define WSZ_ 16
#define NWIN_ (T_ / WSZ_)   // 512
#define TOK_ 128            // tokens per K1 block (= 8 windows)

// ---------------------------------------------------------------------------
// K1 (fused): sims = adjacent cosine sims of g = normalize(relu(z@W1)@W2).
// f32 FMA inner loop, f64 accumulation across 64-long K chunks -> deviation
// from the numpy f32 reference stays at np's own rounding error level.
// Block: 128 tokens x 64 outputs, 256 threads, each 8 tok x 4 gd.
// Windows (16 tokens) never span blocks, so sims are computed in-block and
// g is never written to global memory.
// ---------------------------------------------------------------------------
__global__ __launch_bounds__(256) void k_sims(
    const float* __restrict__ z, const float* __restrict__ W1,
    const float* __restrict__ W2, double* __restrict__ sims_out)
{
  __shared__ float Zs[TOK_][65];   // z tile / H tile / g tile (reused)
  __shared__ float Ws[64][64];     // W1 chunk / W2

  const int tid = threadIdx.x;
  const int ts = tid >> 4;         // 0..15 -> tokens 8*ts .. 8*ts+7
  const int gs = tid & 15;         // 0..15 -> outputs 4*gs .. 4*gs+3
  const long bt0 = (long)blockIdx.x * TOK_;

  double acc64[8][4];
#pragma unroll
  for (int i = 0; i < 8; ++i)
#pragma unroll
    for (int j = 0; j < 4; ++j) acc64[i][j] = 0.0;

  for (int k0 = 0; k0 < D_; k0 += 64) {
    // stage z tile [128 tok][64 k] and W1 chunk [64 k][64 n]
#pragma unroll
    for (int it = 0; it < 8; ++it) {
      const int idx = it * 256 + tid;
      const int tok = idx >> 4, kq = idx & 15;
      *(float4*)&Zs[tok][4 * kq] =
          *(const float4*)(z + (bt0 + tok) * D_ + k0 + 4 * kq);
    }
#pragma unroll
    for (int it = 0; it < 4; ++it) {
      const int idx = it * 256 + tid;
      const int row = idx >> 4, cq = idx & 15;
      *(float4*)&Ws[row][4 * cq] =
          *(const float4*)(W1 + (k0 + row) * GD_ + 4 * cq);
    }
    __syncthreads();

    float acc[8][4];
#pragma unroll
    for (int i = 0; i < 8; ++i)
#pragma unroll
      for (int j = 0; j < 4; ++j) acc[i][j] = 0.0f;

#pragma unroll 4
    for (int k = 0; k < 64; ++k) {
      float zz[8];
#pragma unroll
      for (int i = 0; i < 8; ++i) zz[i] = Zs[ts * 8 + i][k];
      const float4 wv = *(const float4*)&Ws[k][4 * gs];
      const float ww[4] = {wv.x, wv.y, wv.z, wv.w};
#pragma unroll
      for (int i = 0; i < 8; ++i)
#pragma unroll
        for (int j = 0; j < 4; ++j)
          acc[i][j] = fmaf(zz[i], ww[j], acc[i][j]);
    }
#pragma unroll
    for (int i = 0; i < 8; ++i)
#pragma unroll
      for (int j = 0; j < 4; ++j) acc64[i][j] += (double)acc[i][j];
    __syncthreads();
  }

  // H = relu(.), rounded to f32, into Zs[tok][gd]; load W2
#pragma unroll
  for (int i = 0; i < 8; ++i)
#pragma unroll
    for (int j = 0; j < 4; ++j) {
      const double h = acc64[i][j] > 0.0 ? acc64[i][j] : 0.0;
      Zs[ts * 8 + i][4 * gs + j] = (float)h;
    }
#pragma unroll
  for (int it = 0; it < 4; ++it) {
    const int idx = it * 256 + tid;
    const int row = idx >> 4, cq = idx & 15;
    *(float4*)&Ws[row][4 * cq] = *(const float4*)(W2 + row * GD_ + 4 * cq);
  }
  __syncthreads();

  // phase B: G = H @ W2 (K=64, single f32 chunk; error ~2e-7 << np's)
  float acc2[8][4];
#pragma unroll
  for (int i = 0; i < 8; ++i)
#pragma unroll
    for (int j = 0; j < 4; ++j) acc2[i][j] = 0.0f;
#pragma unroll 4
  for (int k = 0; k < 64; ++k) {
    float hh[8];
#pragma unroll
    for (int i = 0; i < 8; ++i) hh[i] = Zs[ts * 8 + i][k];
    const float4 wv = *(const float4*)&Ws[k][4 * gs];
    const float ww[4] = {wv.x, wv.y, wv.z, wv.w};
#pragma unroll
    for (int i = 0; i < 8; ++i)
#pragma unroll
      for (int j = 0; j < 4; ++j)
        acc2[i][j] = fmaf(hh[i], ww[j], acc2[i][j]);
  }
  __syncthreads();

  // normalize (f64 norm of the f32-rounded G), write g into Zs
#pragma unroll
  for (int i = 0; i < 8; ++i) {
    double ss = 0.0;
#pragma unroll
    for (int j = 0; j < 4; ++j)
      ss += (double)acc2[i][j] * (double)acc2[i][j];
#pragma unroll
    for (int m = 1; m < 16; m <<= 1) ss += __shfl_xor(ss, m);
    const double denom = sqrt(ss) + 1e-8;
#pragma unroll
    for (int j = 0; j < 4; ++j)
      Zs[ts * 8 + i][4 * gs + j] = (float)((double)acc2[i][j] / denom);
  }
  __syncthreads();

  // sims: 8 windows x 15 edges per block; one thread per edge, f64 dot
  if (tid < 8 * (WSZ_ - 1)) {
    const int w = tid / (WSZ_ - 1), e = tid % (WSZ_ - 1);
    const int t = w * WSZ_ + e;
    double s = 0.0;
#pragma unroll 8
    for (int d = 0; d < GD_; ++d)
      s += (double)Zs[t][d] * (double)Zs[t + 1][d];
    sims_out[((long)blockIdx.x * 8 + w) * (WSZ_ - 1) + e] = s;
  }
}

// ---------------------------------------------------------------------------
// K2: per-window stable sort + budgeted greedy pick. 1 thread per window.
// ---------------------------------------------------------------------------
__global__ __launch_bounds__(64) void k_pick(
    const double* __restrict__ sims, const int* __restrict__ tlptr,
    int* __restrict__ mrMask, int* __restrict__ keptCnt)
{
  const int win = blockIdx.x * 64 + threadIdx.x;
  if (win >= B_ * NWIN_) return;
  const int w = win % NWIN_;

  const int tl = tlptr[0];
  const int mn = T_ - tl;
  const int base = mn / NWIN_, extra = mn % NWIN_;
  int budget = base + (w < extra ? 1 : 0);
  if (budget > WSZ_ / 2) budget = WSZ_ / 2;
  if (budget < 0) budget = 0;

  double v[WSZ_ - 1];
  int id[WSZ_ - 1];
  for (int e = 0; e < WSZ_ - 1; ++e) {
    v[e] = sims[(long)win * (WSZ_ - 1) + e];
    id[e] = e;
  }
  // stable insertion sort, descending (ties keep smaller index)
  for (int i = 1; i < WSZ_ - 1; ++i) {
    const double dv = v[i]; const int di = id[i];
    int j = i - 1;
    while (j >= 0 && v[j] < dv) { v[j + 1] = v[j]; id[j + 1] = id[j]; --j; }
    v[j + 1] = dv; id[j + 1] = di;
  }
  bool used[WSZ_];
  for (int i = 0; i < WSZ_; ++i) used[i] = false;
  int mrm = 0, picked = 0;
  for (int ii = 0; ii < WSZ_ - 1; ++ii) {
    const int e = id[ii];
    if (picked < budget && !used[e] && !used[e + 1]) {
      used[e] = used[e + 1] = true;
      mrm |= (1 << (e + 1));
      ++picked;
    }
  }
  mrMask[win] = mrm;
  keptCnt[win] = WSZ_ - picked;
}

// ---------------------------------------------------------------------------
// K3: per-batch exclusive prefix over window kept-counts (tiny)
// ---------------------------------------------------------------------------
__global__ void k_scan_windows(const int* __restrict__ keptCnt,
                               int* __restrict__ outOff)
{
  const int b = threadIdx.x;
  if (b >= B_) return;
  int off = 0;
  for (int w = 0; w < NWIN_; ++w) {
    outOff[b * NWIN_ + w] = off;
    off += keptCnt[b * NWIN_ + w];
  }
}

// ---------------------------------------------------------------------------
// K4: emit z_new rows + lens_new.  grid: B*NWIN blocks, 256 threads.
// ---------------------------------------------------------------------------
__global__ __launch_bounds__(256) void k_emit(
    const float* __restrict__ z, const int* __restrict__ lens,
    const int* __restrict__ mrMask, const int* __restrict__ outOff,
    float* __restrict__ out, int TL)
{
  const int bw = blockIdx.x;
  const int b = bw / NWIN_, w = bw % NWIN_;
  const int tid = threadIdx.x;
  const int mrm = mrMask[bw];
  int p = outOff[bw];
  const int t0 = w * WSZ_;

  const float* zb = z + (long)b * T_ * D_;
  const int* lb = lens + b * T_;
  float* zout = out;
  float* lout = out + (long)B_ * TL * D_;

  for (int i = 0; i < WSZ_; ++i) {
    if ((mrm >> i) & 1) continue;   // dropped token
    if (p >= TL) return;            // uniform across block
    const int t = t0 + i;
    const bool ab = (i < WSZ_ - 1) && ((mrm >> (i + 1)) & 1);
    float4 o = *(const float4*)(zb + (long)t * D_ + tid * 4);
    if (ab) {
      const float wi = (float)lb[t], wj = (float)lb[t + 1];
      const float s = wi + wj;
      const float4 zj = *(const float4*)(zb + (long)(t + 1) * D_ + tid * 4);
      o.x = (o.x * wi + zj.x * wj) / s;
      o.y = (o.y * wi + zj.y * wj) / s;
      o.z = (o.z * wi + zj.z * wj) / s;
      o.w = (o.w * wi + zj.w * wj) / s;
      if (tid == 0) lout[(long)b * TL + p] = s;
    } else {
      if (tid == 0) lout[(long)b * TL + p] = (float)lb[t];
    }
    *(float4*)(zout + ((long)b * TL + p) * D_ + tid * 4) = o;
    ++p;
  }
}

// ---------------------------------------------------------------------------
// K5: starts = exclusive cumsum of lens_new per row. grid: B blocks, 256 thr.
// ---------------------------------------------------------------------------
__global__ __launch_bounds__(256) void k_starts(
    const float* __restrict__ lens_f, float* __restrict__ starts, int TL)
{
  const int b = blockIdx.x;
  const int tid = threadIdx.x;
  const int lane = tid & 63, wv = tid >> 6;
  __shared__ float wsum[4];
  const float* lrow = lens_f + (long)b * TL;
  float* srow = starts + (long)b * TL;
  float carry = 0.0f;

  for (int c0 = 0; c0 < TL; c0 += 256) {
    const int j = c0 + tid;
    const float v = (j < TL) ? lrow[j] : 0.0f;
    float x = v;
#pragma unroll
    for (int d = 1; d < 64; d <<= 1) {
      const float o = __shfl_up(x, d);
      if (lane >= d) x += o;
    }
    if (lane == 63) wsum[wv] = x;
    __syncthreads();
    float pre = 0.0f;
    if (wv > 0) pre += wsum[0];
    if (wv > 1) pre += wsum[1];
    if (wv > 2) pre += wsum[2];
    const float tot = wsum[0] + wsum[1] + wsum[2] + wsum[3];
    if (j < TL) srow[j] = carry + pre + x - v;
    carry += tot;
    __syncthreads();
  }
}

// ---------------------------------------------------------------------------
extern "C" void kernel_launch(void* const* d_in, const int* in_sizes, int n_in,
                              void* d_out, int out_size, void* d_ws, size_t ws_size,
                              hipStream_t stream)
{
  const float* z    = (const float*)d_in[0];
  const int*   lens = (const int*)d_in[1];
  const float* W1   = (const float*)d_in[2];
  const float* W2   = (const float*)d_in[3];
  const int*   tlp  = (const int*)d_in[4];

  float* out = (float*)d_out;
  const int TL = out_size / (B_ * (D_ + 2));   // 6144

  // workspace layout
  double* sims  = (double*)d_ws;                               // 4096*15 f64
  int* mrMask = (int*)((char*)d_ws + (size_t)B_ * NWIN_ * (WSZ_ - 1) * 8);
  int* kept   = mrMask + B_ * NWIN_;
  int* outOff = kept + B_ * NWIN_;

  hipLaunchKernelGGL(k_sims, dim3((B_ * T_) / TOK_), dim3(256), 0, stream,
                     z, W1, W2, sims);
  hipLaunchKernelGGL(k_pick, dim3((B_ * NWIN_ + 63) / 64), dim3(64), 0, stream,
                     sims, tlp, mrMask, kept);
  hipLaunchKernelGGL(k_scan_windows, dim3(1), dim3(64), 0, stream,
                     kept, outOff);
  hipLaunchKernelGGL(k_emit, dim3(B_ * NWIN_), dim3(256), 0, stream,
                     z, lens, mrMask, outOff, out, TL);
  hipLaunchKernelGGL(k_starts, dim3(B_), dim3(256), 0, stream,
                     out + (long)B_ * TL * D_,
                     out + (long)B_ * TL * D_ + (long)B_ * TL, TL);
}